// Round 1
// baseline (11536.185 us; speedup 1.0000x reference)
//
#include <hip/hip_runtime.h>
#include <stdint.h>

#define BB 64
#define SS 128   // decoder steps
#define EE 1024  // encoder T
#define HH 512
#define DD 512   // enc_D
#define AA 512
#define VV 128
#define KX 1536  // [emb, ctx, h]
#define NC 2048  // G columns: r,z combined | gi_n | gh_n

#define AW_OFF ((size_t)BB*SS*VV)            // 1048576
#define OC_OFF (AW_OFF + (size_t)BB*SS*EE)   // 9437184

typedef unsigned short u16;

__device__ __forceinline__ float sigmoid_f(float x){
  return __builtin_amdgcn_rcpf(1.f + __expf(-x));
}
__device__ __forceinline__ float tanh_f(float x){
  float e = __expf(2.f*x);                 // inf-safe: rcp(inf)=0 -> 1 ; e->0 -> -1
  return 1.f - 2.f*__builtin_amdgcn_rcpf(e + 1.f);
}
__device__ __forceinline__ u16 f2bf(float f){
  uint32_t u = __float_as_uint(f);
  return (u16)((u + 0x7fffu + ((u>>16)&1u)) >> 16);
}

// ---------------- P0: build Wbig, wqT, wvT, fcT, bias_big ----------------
__global__ void k_build(const float* __restrict__ w_ih, const float* __restrict__ w_hh,
                        const float* __restrict__ b_ih, const float* __restrict__ b_hh,
                        const float* __restrict__ wq,   const float* __restrict__ wv,
                        const float* __restrict__ fc_w,
                        float* __restrict__ Wbig, float* __restrict__ wqT,
                        float* __restrict__ wvT,  float* __restrict__ fcT,
                        float* __restrict__ bias_big){
  int i = blockIdx.x*256 + threadIdx.x;
  const int NW = KX*NC;
  if (i < NW){
    int k = i >> 11, c = i & (NC-1);
    float v;
    if (c < 1024)      v = (k < 1024) ? w_ih[c*1024 + k] : w_hh[c*512 + (k-1024)];
    else if (c < 1536) v = (k < 1024) ? w_ih[c*1024 + k] : 0.f;
    else               v = (k >= 1024) ? w_hh[(c-512)*512 + (k-1024)] : 0.f;
    Wbig[i] = v; return;
  }
  i -= NW;
  if (i < 512*512){ int j = i >> 9, a = i & 511; wqT[i] = wq[a*512 + j]; return; }
  i -= 512*512;
  if (i < 512*512){ int e = i >> 9, a = i & 511; wvT[i] = wv[a*512 + e]; return; }
  i -= 512*512;
  if (i < 1024*128){ int k = i >> 7, v = i & 127; fcT[i] = fc_w[v*1024 + k]; return; }
  i -= 1024*128;
  if (i < NC){
    float bv;
    if (i < 1024)      bv = b_ih[i] + b_hh[i];
    else if (i < 1536) bv = b_ih[i];
    else               bv = b_hh[i - 512];
    bias_big[i] = bv;
  }
}

// ---------------- P1: encp = enc @ wvT + (attn_bias+conv_b), bf16 --------
__global__ __launch_bounds__(256) void k_encp(const float* __restrict__ enc,
                                              const float* __restrict__ wvT,
                                              const float* __restrict__ abias,
                                              const float* __restrict__ convb,
                                              u16* __restrict__ encp){
  __shared__ float As[64][36];
  __shared__ float Bs[32][68];
  int tid = threadIdx.x;
  int r0 = blockIdx.x * 64;
  int a0 = blockIdx.y * 64;
  float4 acc[4];
  #pragma unroll
  for (int r = 0; r < 4; ++r) acc[r] = make_float4(0.f,0.f,0.f,0.f);
  int rl = tid >> 2, kl0 = (tid & 3) * 8;
  int kl2 = tid >> 3, al0 = (tid & 7) * 8;
  int br = (tid >> 4) * 4, cc = (tid & 15) * 4;
  for (int kk = 0; kk < 512; kk += 32){
    float4 av0 = *(const float4*)&enc[(size_t)(r0+rl)*512 + kk + kl0];
    float4 av1 = *(const float4*)&enc[(size_t)(r0+rl)*512 + kk + kl0 + 4];
    float4 bv0 = *(const float4*)&wvT[(size_t)(kk+kl2)*512 + a0 + al0];
    float4 bv1 = *(const float4*)&wvT[(size_t)(kk+kl2)*512 + a0 + al0 + 4];
    __syncthreads();
    *(float4*)&As[rl][kl0]     = av0;
    *(float4*)&As[rl][kl0+4]   = av1;
    *(float4*)&Bs[kl2][al0]    = bv0;
    *(float4*)&Bs[kl2][al0+4]  = bv1;
    __syncthreads();
    #pragma unroll
    for (int i = 0; i < 32; ++i){
      float4 b4 = *(const float4*)&Bs[i][cc];
      float x0 = As[br][i], x1 = As[br+1][i], x2 = As[br+2][i], x3 = As[br+3][i];
      acc[0].x += x0*b4.x; acc[0].y += x0*b4.y; acc[0].z += x0*b4.z; acc[0].w += x0*b4.w;
      acc[1].x += x1*b4.x; acc[1].y += x1*b4.y; acc[1].z += x1*b4.z; acc[1].w += x1*b4.w;
      acc[2].x += x2*b4.x; acc[2].y += x2*b4.y; acc[2].z += x2*b4.z; acc[2].w += x2*b4.w;
      acc[3].x += x3*b4.x; acc[3].y += x3*b4.y; acc[3].z += x3*b4.z; acc[3].w += x3*b4.w;
    }
  }
  int a = a0 + cc;
  float b0f = abias[a]   + convb[a];
  float b1f = abias[a+1] + convb[a+1];
  float b2f_ = abias[a+2] + convb[a+2];
  float b3f = abias[a+3] + convb[a+3];
  #pragma unroll
  for (int r = 0; r < 4; ++r){
    size_t row = (size_t)(r0 + br + r);
    ushort4 pk;
    pk.x = f2bf(acc[r].x + b0f);
    pk.y = f2bf(acc[r].y + b1f);
    pk.z = f2bf(acc[r].z + b2f_);
    pk.w = f2bf(acc[r].w + b3f);
    *(ushort4*)&encp[row*512 + a] = pk;
  }
}

// ---------------- K1: G partials = [emb,ctx,h] @ Wbig (K-split) ----------
__global__ __launch_bounds__(256) void k_ggemm(const int* __restrict__ inputs,
                                               const float* __restrict__ emb,
                                               const float* __restrict__ ctx,
                                               const float* __restrict__ h,
                                               const float* __restrict__ Wbig,
                                               float* __restrict__ Gp, int s){
  __shared__ float Xs[64][36];
  __shared__ float Ws[32][68];
  int tid = threadIdx.x;
  int c0 = blockIdx.x * 64;
  int kc = blockIdx.y;
  int kbase = kc * 192;
  float4 acc[4];
  #pragma unroll
  for (int r = 0; r < 4; ++r) acc[r] = make_float4(0.f,0.f,0.f,0.f);
  int bl = tid >> 2, kl0 = (tid & 3) * 8;
  int kw = tid >> 3, cl0 = (tid & 7) * 8;
  int br = (tid >> 4) * 4, cc = (tid & 15) * 4;
  const float* emb_b = emb + (size_t)inputs[bl*SS + s]*HH;
  bool t0 = (s == 0);
  for (int kk = 0; kk < 192; kk += 32){
    float xv[8];
    #pragma unroll
    for (int u = 0; u < 8; ++u){
      int kg = kbase + kk + kl0 + u;
      float v;
      if (kg < 512)       v = emb_b[kg];
      else if (kg < 1024) v = t0 ? 0.f : ctx[bl*512 + kg - 512];
      else                v = t0 ? 0.f : h[bl*512 + kg - 1024];
      xv[u] = v;
    }
    float4 w1 = *(const float4*)&Wbig[(size_t)(kbase+kk+kw)*NC + c0 + cl0];
    float4 w2 = *(const float4*)&Wbig[(size_t)(kbase+kk+kw)*NC + c0 + cl0 + 4];
    __syncthreads();
    *(float4*)&Xs[bl][kl0]   = make_float4(xv[0],xv[1],xv[2],xv[3]);
    *(float4*)&Xs[bl][kl0+4] = make_float4(xv[4],xv[5],xv[6],xv[7]);
    *(float4*)&Ws[kw][cl0]   = w1;
    *(float4*)&Ws[kw][cl0+4] = w2;
    __syncthreads();
    #pragma unroll
    for (int i = 0; i < 32; ++i){
      float4 b4 = *(const float4*)&Ws[i][cc];
      float x0 = Xs[br][i], x1 = Xs[br+1][i], x2 = Xs[br+2][i], x3 = Xs[br+3][i];
      acc[0].x += x0*b4.x; acc[0].y += x0*b4.y; acc[0].z += x0*b4.z; acc[0].w += x0*b4.w;
      acc[1].x += x1*b4.x; acc[1].y += x1*b4.y; acc[1].z += x1*b4.z; acc[1].w += x1*b4.w;
      acc[2].x += x2*b4.x; acc[2].y += x2*b4.y; acc[2].z += x2*b4.z; acc[2].w += x2*b4.w;
      acc[3].x += x3*b4.x; acc[3].y += x3*b4.y; acc[3].z += x3*b4.z; acc[3].w += x3*b4.w;
    }
  }
  #pragma unroll
  for (int r = 0; r < 4; ++r)
    *(float4*)&Gp[(size_t)(kc*64 + br + r)*NC + c0 + cc] = acc[r];
}

// ---------------- K2: gates -> h_new ; q partials -------------------------
__global__ __launch_bounds__(256) void k_gate_q(const float* __restrict__ Gp,
                                                const float* __restrict__ bias_big,
                                                float* __restrict__ h,
                                                const float* __restrict__ wqT,
                                                float* __restrict__ qp,
                                                float* __restrict__ out, int s){
  __shared__ float h_l[512];
  int tid = threadIdx.x;
  int jt = blockIdx.x, bt = blockIdx.y;
  bool t0 = (s == 0);
  #pragma unroll
  for (int it = 0; it < 2; ++it){
    int item = tid + it*256;
    int bi = item >> 6, jl = item & 63;
    int b = bt*8 + bi, j = jt*64 + jl;
    float s0=0.f, s1=0.f, s2=0.f, s3=0.f;
    #pragma unroll
    for (int kc = 0; kc < 8; ++kc){
      const float* g = Gp + (size_t)(kc*64 + b)*NC;
      s0 += g[j]; s1 += g[512+j]; s2 += g[1024+j]; s3 += g[1536+j];
    }
    float r = sigmoid_f(s0 + bias_big[j]);
    float z = sigmoid_f(s1 + bias_big[512+j]);
    float n = tanh_f(s2 + bias_big[1024+j] + r*(s3 + bias_big[1536+j]));
    float hold = t0 ? 0.f : h[b*512 + j];
    float hn = (1.f - z)*n + z*hold;
    h_l[item] = hn;
    h[b*512 + j] = hn;
    out[OC_OFF + (size_t)(b*SS + s)*1024 + j] = hn;
  }
  __syncthreads();
  int a0 = tid*2;
  float2 acc8[8];
  #pragma unroll
  for (int bi = 0; bi < 8; ++bi) acc8[bi] = make_float2(0.f, 0.f);
  for (int j = 0; j < 64; ++j){
    float2 w = *(const float2*)&wqT[(size_t)(jt*64 + j)*512 + a0];
    #pragma unroll
    for (int bi = 0; bi < 8; ++bi){
      float hv = h_l[bi*64 + j];
      acc8[bi].x += hv*w.x; acc8[bi].y += hv*w.y;
    }
  }
  #pragma unroll
  for (int bi = 0; bi < 8; ++bi)
    *(float2*)&qp[(size_t)(jt*64 + bt*8 + bi)*512 + a0] = acc8[bi];
}

// ---------------- K3: scores --------------------------------------------
__global__ __launch_bounds__(1024) void k_score(const float* __restrict__ qp,
                                                const float* __restrict__ attn_v,
                                                const float* __restrict__ conv_w,
                                                const u16* __restrict__ encp,
                                                const float* __restrict__ out_aw,
                                                float* __restrict__ score, int s){
  __shared__ float q_l[512], v_l[512], c0_l[512], c1_l[512], c2_l[512];
  int tid = threadIdx.x;
  int b = blockIdx.y, et = blockIdx.x;
  if (tid < 512){
    float qq = 0.f;
    #pragma unroll
    for (int jt = 0; jt < 8; ++jt) qq += qp[(size_t)(jt*64 + b)*512 + tid];
    q_l[tid]  = qq;
    v_l[tid]  = attn_v[tid];
    c0_l[tid] = conv_w[tid*3 + 0];
    c1_l[tid] = conv_w[tid*3 + 1];
    c2_l[tid] = conv_w[tid*3 + 2];
  }
  __syncthreads();
  int wave = tid >> 6, lane = tid & 63;
  float q8[8], v8[8], c08[8], c18[8], c28[8];
  #pragma unroll
  for (int i = 0; i < 8; ++i){
    int a = lane*8 + i;
    q8[i] = q_l[a]; v8[i] = v_l[a]; c08[i] = c0_l[a]; c18[i] = c1_l[a]; c28[i] = c2_l[a];
  }
  const float* awrow = out_aw + AW_OFF + (size_t)(b*SS + (s-1))*EE;
  #pragma unroll
  for (int eu = 0; eu < 8; ++eu){
    int e = et*128 + wave*8 + eu;
    float wl = 0.f, wc = 0.f, wr = 0.f;
    if (s > 0){
      wc = awrow[e];
      wl = (e > 0)    ? awrow[e-1] : 0.f;
      wr = (e < EE-1) ? awrow[e+1] : 0.f;
    }
    uint4 pk = *(const uint4*)(encp + ((size_t)(b*EE + e)*512 + lane*8));
    uint32_t ua[4] = {pk.x, pk.y, pk.z, pk.w};
    float acc = 0.f;
    #pragma unroll
    for (int p = 0; p < 4; ++p){
      float plo = __uint_as_float(ua[p] << 16);
      float phi = __uint_as_float(ua[p] & 0xffff0000u);
      int i = p*2;
      float v0 = q8[i]   + plo + c08[i]*wl   + c18[i]*wc   + c28[i]*wr;
      acc += tanh_f(v0) * v8[i];
      float v1 = q8[i+1] + phi + c08[i+1]*wl + c18[i+1]*wc + c28[i+1]*wr;
      acc += tanh_f(v1) * v8[i+1];
    }
    #pragma unroll
    for (int off = 32; off; off >>= 1) acc += __shfl_xor(acc, off, 64);
    if (lane == 0) score[b*EE + e] = acc;
  }
}

// ---------------- K4: softmax + aw out + ctx partials ---------------------
__global__ __launch_bounds__(256) void k_soft_ctx(const float* __restrict__ score,
                                                  const float* __restrict__ enc,
                                                  float* __restrict__ ctxp,
                                                  float* __restrict__ out, int s){
  __shared__ float s_l[1024];
  __shared__ float red[256];
  __shared__ float w_l[128];
  int tid = threadIdx.x;
  int c = blockIdx.x, b = blockIdx.y;
  float lv[4];
  #pragma unroll
  for (int u = 0; u < 4; ++u){
    lv[u] = score[b*EE + u*256 + tid];
    s_l[u*256 + tid] = lv[u];
  }
  float m = fmaxf(fmaxf(lv[0], lv[1]), fmaxf(lv[2], lv[3]));
  red[tid] = m; __syncthreads();
  for (int st = 128; st > 0; st >>= 1){
    if (tid < st) red[tid] = fmaxf(red[tid], red[tid+st]);
    __syncthreads();
  }
  m = red[0]; __syncthreads();
  float sm = 0.f;
  #pragma unroll
  for (int u = 0; u < 4; ++u) sm += __expf(lv[u] - m);
  red[tid] = sm; __syncthreads();
  for (int st = 128; st > 0; st >>= 1){
    if (tid < st) red[tid] += red[tid+st];
    __syncthreads();
  }
  float rS = __builtin_amdgcn_rcpf(red[0]);
  if (tid < 128){
    int e = c*128 + tid;
    float w = __expf(s_l[e] - m) * rS;
    w_l[tid] = w;
    out[AW_OFF + (size_t)(b*SS + s)*EE + e] = w;
  }
  __syncthreads();
  int d0 = tid*2;
  float a0 = 0.f, a1 = 0.f;
  for (int i = 0; i < 128; ++i){
    float2 ev = *(const float2*)&enc[((size_t)b*EE + c*128 + i)*512 + d0];
    float w = w_l[i];
    a0 += w*ev.x; a1 += w*ev.y;
  }
  *(float2*)&ctxp[(size_t)(c*64 + b)*512 + d0] = make_float2(a0, a1);
}

// ---------------- K5: ctx reduce + fc + log_softmax -----------------------
__global__ __launch_bounds__(256) void k_fc(const float* __restrict__ h,
                                            const float* __restrict__ ctxp,
                                            float* __restrict__ ctx,
                                            const float* __restrict__ fcT,
                                            const float* __restrict__ fc_b,
                                            float* __restrict__ out, int s){
  __shared__ float oc_l[1024];
  __shared__ float lp[2][128];
  __shared__ float l_l[128];
  int tid = threadIdx.x, b = blockIdx.x;
  oc_l[tid]       = h[b*512 + tid];
  oc_l[tid + 256] = h[b*512 + tid + 256];
  int d0 = tid*2;
  float a0 = 0.f, a1 = 0.f;
  #pragma unroll
  for (int cc = 0; cc < 8; ++cc){
    float2 p = *(const float2*)&ctxp[(size_t)(cc*64 + b)*512 + d0];
    a0 += p.x; a1 += p.y;
  }
  oc_l[512 + d0]     = a0;
  oc_l[512 + d0 + 1] = a1;
  ctx[b*512 + d0]     = a0;
  ctx[b*512 + d0 + 1] = a1;
  size_t oco = OC_OFF + (size_t)(b*SS + s)*1024 + 512 + d0;
  out[oco]     = a0;
  out[oco + 1] = a1;
  __syncthreads();
  int v = tid & 127, half = tid >> 7;
  float acc = 0.f;
  #pragma unroll 8
  for (int k = 0; k < 512; ++k)
    acc += oc_l[half*512 + k] * fcT[(size_t)(half*512 + k)*128 + v];
  lp[half][v] = acc;
  __syncthreads();
  if (tid < 128) l_l[tid] = lp[0][tid] + lp[1][tid] + fc_b[tid];
  __syncthreads();
  if (tid < 128){
    float m = -1e30f;
    for (int i = 0; i < 128; ++i) m = fmaxf(m, l_l[i]);
    float sm = 0.f;
    for (int i = 0; i < 128; ++i) sm += __expf(l_l[i] - m);
    out[(size_t)(b*SS + s)*VV + tid] = l_l[tid] - m - __logf(sm);
  }
}

extern "C" void kernel_launch(void* const* d_in, const int* in_sizes, int n_in,
                              void* d_out, int out_size, void* d_ws, size_t ws_size,
                              hipStream_t stream){
  (void)in_sizes; (void)n_in; (void)out_size; (void)ws_size;
  const int*   inputs = (const int*)d_in[0];
  const float* enc    = (const float*)d_in[1];
  const float* emb    = (const float*)d_in[2];
  const float* w_ih   = (const float*)d_in[3];
  const float* w_hh   = (const float*)d_in[4];
  const float* b_ih   = (const float*)d_in[5];
  const float* b_hh   = (const float*)d_in[6];
  const float* wq     = (const float*)d_in[7];
  const float* wv     = (const float*)d_in[8];
  const float* convw  = (const float*)d_in[9];
  const float* convb  = (const float*)d_in[10];
  const float* abias  = (const float*)d_in[11];
  const float* av     = (const float*)d_in[12];
  const float* fcw    = (const float*)d_in[13];
  const float* fcb    = (const float*)d_in[14];
  float* out = (float*)d_out;

  char* p = (char*)d_ws;
  auto alloc = [&](size_t bytes)->char*{
    char* r = p; p += (bytes + 255) & ~(size_t)255; return r;
  };
  u16*   encp  = (u16*)  alloc((size_t)BB*EE*AA*2);   // 67 MB
  float* Wbig  = (float*)alloc((size_t)KX*NC*4);      // 12.6 MB
  float* wqT   = (float*)alloc((size_t)512*512*4);
  float* wvT   = (float*)alloc((size_t)512*512*4);
  float* fcT   = (float*)alloc((size_t)1024*128*4);
  float* biasb = (float*)alloc((size_t)NC*4);
  float* hbuf  = (float*)alloc((size_t)BB*HH*4);
  float* ctx   = (float*)alloc((size_t)BB*DD*4);
  float* Gp    = (float*)alloc((size_t)8*BB*NC*4);    // 4 MB
  float* qp    = (float*)alloc((size_t)8*BB*AA*4);    // 1 MB
  float* score = (float*)alloc((size_t)BB*EE*4);
  float* ctxp  = (float*)alloc((size_t)8*BB*DD*4);    // 1 MB

  int total0 = KX*NC + 512*512 + 512*512 + 1024*128 + NC;
  k_build<<<(total0 + 255)/256, 256, 0, stream>>>(w_ih, w_hh, b_ih, b_hh, wq, wv, fcw,
                                                  Wbig, wqT, wvT, fcT, biasb);
  k_encp<<<dim3(1024, 8), 256, 0, stream>>>(enc, wvT, abias, convb, encp);

  for (int s = 0; s < SS; ++s){
    k_ggemm<<<dim3(32, 8), 256, 0, stream>>>(inputs, emb, ctx, hbuf, Wbig, Gp, s);
    k_gate_q<<<dim3(8, 8), 256, 0, stream>>>(Gp, biasb, hbuf, wqT, qp, out, s);
    k_score<<<dim3(8, 64), 1024, 0, stream>>>(qp, av, convw, encp, out, score, s);
    k_soft_ctx<<<dim3(8, 64), 256, 0, stream>>>(score, enc, ctxp, out, s);
    k_fc<<<64, 256, 0, stream>>>(hbuf, ctxp, ctx, fcT, fcb, out, s);
  }
}

// Round 2
// 10038.650 us; speedup vs baseline: 1.1492x; 1.1492x over previous
//
#include <hip/hip_runtime.h>
#include <stdint.h>

#define BB 64
#define SS 128   // decoder steps
#define EE 1024  // encoder T
#define HH 512
#define DD 512   // enc_D
#define AA 512
#define VV 128
#define KX 1536  // [emb, ctx, h]
#define NC 2048  // G columns: r,z combined | gi_n | gh_n

#define AW_OFF ((size_t)BB*SS*VV)            // 1048576
#define OC_OFF (AW_OFF + (size_t)BB*SS*EE)   // 9437184

typedef unsigned short u16;

__device__ __forceinline__ float sigmoid_f(float x){
  return __builtin_amdgcn_rcpf(1.f + __expf(-x));
}
__device__ __forceinline__ float tanh_f(float x){
  float e = __expf(2.f*x);                 // inf-safe: rcp(inf)=0 -> 1 ; e->0 -> -1
  return 1.f - 2.f*__builtin_amdgcn_rcpf(e + 1.f);
}
__device__ __forceinline__ u16 f2bf(float f){
  uint32_t u = __float_as_uint(f);
  return (u16)((u + 0x7fffu + ((u>>16)&1u)) >> 16);
}

// ---------------- P0: build Wbig, wqT, wvT, fcT, bias_big ----------------
__global__ void k_build(const float* __restrict__ w_ih, const float* __restrict__ w_hh,
                        const float* __restrict__ b_ih, const float* __restrict__ b_hh,
                        const float* __restrict__ wq,   const float* __restrict__ wv,
                        const float* __restrict__ fc_w,
                        float* __restrict__ Wbig, float* __restrict__ wqT,
                        float* __restrict__ wvT,  float* __restrict__ fcT,
                        float* __restrict__ bias_big){
  int i = blockIdx.x*256 + threadIdx.x;
  const int NW = KX*NC;
  if (i < NW){
    int k = i >> 11, c = i & (NC-1);
    float v;
    if (c < 1024)      v = (k < 1024) ? w_ih[c*1024 + k] : w_hh[c*512 + (k-1024)];
    else if (c < 1536) v = (k < 1024) ? w_ih[c*1024 + k] : 0.f;
    else               v = (k >= 1024) ? w_hh[(c-512)*512 + (k-1024)] : 0.f;
    Wbig[i] = v; return;
  }
  i -= NW;
  if (i < 512*512){ int j = i >> 9, a = i & 511; wqT[i] = wq[a*512 + j]; return; }
  i -= 512*512;
  if (i < 512*512){ int e = i >> 9, a = i & 511; wvT[i] = wv[a*512 + e]; return; }
  i -= 512*512;
  if (i < 1024*128){ int k = i >> 7, v = i & 127; fcT[i] = fc_w[v*1024 + k]; return; }
  i -= 1024*128;
  if (i < NC){
    float bv;
    if (i < 1024)      bv = b_ih[i] + b_hh[i];
    else if (i < 1536) bv = b_ih[i];
    else               bv = b_hh[i - 512];
    bias_big[i] = bv;
  }
}

// ---------------- P1: encp = enc @ wvT + (attn_bias+conv_b), bf16 --------
__global__ __launch_bounds__(256) void k_encp(const float* __restrict__ enc,
                                              const float* __restrict__ wvT,
                                              const float* __restrict__ abias,
                                              const float* __restrict__ convb,
                                              u16* __restrict__ encp){
  __shared__ float As[64][36];
  __shared__ float Bs[32][68];
  int tid = threadIdx.x;
  int r0 = blockIdx.x * 64;
  int a0 = blockIdx.y * 64;
  float4 acc[4];
  #pragma unroll
  for (int r = 0; r < 4; ++r) acc[r] = make_float4(0.f,0.f,0.f,0.f);
  int rl = tid >> 2, kl0 = (tid & 3) * 8;
  int kl2 = tid >> 3, al0 = (tid & 7) * 8;
  int br = (tid >> 4) * 4, cc = (tid & 15) * 4;
  for (int kk = 0; kk < 512; kk += 32){
    float4 av0 = *(const float4*)&enc[(size_t)(r0+rl)*512 + kk + kl0];
    float4 av1 = *(const float4*)&enc[(size_t)(r0+rl)*512 + kk + kl0 + 4];
    float4 bv0 = *(const float4*)&wvT[(size_t)(kk+kl2)*512 + a0 + al0];
    float4 bv1 = *(const float4*)&wvT[(size_t)(kk+kl2)*512 + a0 + al0 + 4];
    __syncthreads();
    *(float4*)&As[rl][kl0]     = av0;
    *(float4*)&As[rl][kl0+4]   = av1;
    *(float4*)&Bs[kl2][al0]    = bv0;
    *(float4*)&Bs[kl2][al0+4]  = bv1;
    __syncthreads();
    #pragma unroll
    for (int i = 0; i < 32; ++i){
      float4 b4 = *(const float4*)&Bs[i][cc];
      float x0 = As[br][i], x1 = As[br+1][i], x2 = As[br+2][i], x3 = As[br+3][i];
      acc[0].x += x0*b4.x; acc[0].y += x0*b4.y; acc[0].z += x0*b4.z; acc[0].w += x0*b4.w;
      acc[1].x += x1*b4.x; acc[1].y += x1*b4.y; acc[1].z += x1*b4.z; acc[1].w += x1*b4.w;
      acc[2].x += x2*b4.x; acc[2].y += x2*b4.y; acc[2].z += x2*b4.z; acc[2].w += x2*b4.w;
      acc[3].x += x3*b4.x; acc[3].y += x3*b4.y; acc[3].z += x3*b4.z; acc[3].w += x3*b4.w;
    }
  }
  int a = a0 + cc;
  float b0f = abias[a]   + convb[a];
  float b1f = abias[a+1] + convb[a+1];
  float b2f_ = abias[a+2] + convb[a+2];
  float b3f = abias[a+3] + convb[a+3];
  #pragma unroll
  for (int r = 0; r < 4; ++r){
    size_t row = (size_t)(r0 + br + r);
    ushort4 pk;
    pk.x = f2bf(acc[r].x + b0f);
    pk.y = f2bf(acc[r].y + b1f);
    pk.z = f2bf(acc[r].z + b2f_);
    pk.w = f2bf(acc[r].w + b3f);
    *(ushort4*)&encp[row*512 + a] = pk;
  }
}

// ---------------- P2: enc f32 -> bf16 copy --------------------------------
__global__ __launch_bounds__(256) void k_encbf(const float* __restrict__ enc,
                                               u16* __restrict__ enc_bf){
  size_t i = ((size_t)blockIdx.x*256 + threadIdx.x) * 4;
  float4 v = *(const float4*)&enc[i];
  ushort4 pk;
  pk.x = f2bf(v.x); pk.y = f2bf(v.y); pk.z = f2bf(v.z); pk.w = f2bf(v.w);
  *(ushort4*)&enc_bf[i] = pk;
}

// ---------------- KA: G partials = [emb,ctx,h] @ Wbig  (+ fused fc(s-1)) --
__global__ __launch_bounds__(256) void k_ggemm_fc(const int* __restrict__ inputs,
                                                  const float* __restrict__ emb,
                                                  const float* __restrict__ ctxp,
                                                  const float* __restrict__ h,
                                                  const float* __restrict__ Wbig,
                                                  float* __restrict__ Gp,
                                                  const float* __restrict__ fcT,
                                                  const float* __restrict__ fc_b,
                                                  float* __restrict__ out,
                                                  int s, int gemm_nb, int sfc){
  int tid = threadIdx.x;
  if ((int)blockIdx.x < gemm_nb){
    // ---- GEMM path ----
    __shared__ float Xs[64][36];
    __shared__ float Ws[32][68];
    int bid = blockIdx.x;
    int c0 = (bid & 31) * 64;
    int kc = bid >> 5;
    int kbase = kc * 192;
    float4 acc[4];
    #pragma unroll
    for (int r = 0; r < 4; ++r) acc[r] = make_float4(0.f,0.f,0.f,0.f);
    int bl = tid >> 2, kl0 = (tid & 3) * 8;
    int kw = tid >> 3, cl0 = (tid & 7) * 8;
    int br = (tid >> 4) * 4, cc = (tid & 15) * 4;
    const float* emb_b = emb + (size_t)inputs[bl*SS + s]*HH;
    bool t0 = (s == 0);
    for (int kk = 0; kk < 192; kk += 32){
      float xv[8];
      #pragma unroll
      for (int u = 0; u < 8; ++u){
        int kg = kbase + kk + kl0 + u;
        float v;
        if (kg < 512)       v = emb_b[kg];
        else if (kg < 1024){
          if (t0) v = 0.f;
          else {
            int d = kg - 512;
            v = ctxp[(size_t)(0*64+bl)*512 + d] + ctxp[(size_t)(1*64+bl)*512 + d]
              + ctxp[(size_t)(2*64+bl)*512 + d] + ctxp[(size_t)(3*64+bl)*512 + d];
          }
        }
        else                v = t0 ? 0.f : h[bl*512 + kg - 1024];
        xv[u] = v;
      }
      float4 w1 = *(const float4*)&Wbig[(size_t)(kbase+kk+kw)*NC + c0 + cl0];
      float4 w2 = *(const float4*)&Wbig[(size_t)(kbase+kk+kw)*NC + c0 + cl0 + 4];
      __syncthreads();
      *(float4*)&Xs[bl][kl0]   = make_float4(xv[0],xv[1],xv[2],xv[3]);
      *(float4*)&Xs[bl][kl0+4] = make_float4(xv[4],xv[5],xv[6],xv[7]);
      *(float4*)&Ws[kw][cl0]   = w1;
      *(float4*)&Ws[kw][cl0+4] = w2;
      __syncthreads();
      #pragma unroll
      for (int i = 0; i < 32; ++i){
        float4 b4 = *(const float4*)&Ws[i][cc];
        float x0 = Xs[br][i], x1 = Xs[br+1][i], x2 = Xs[br+2][i], x3 = Xs[br+3][i];
        acc[0].x += x0*b4.x; acc[0].y += x0*b4.y; acc[0].z += x0*b4.z; acc[0].w += x0*b4.w;
        acc[1].x += x1*b4.x; acc[1].y += x1*b4.y; acc[1].z += x1*b4.z; acc[1].w += x1*b4.w;
        acc[2].x += x2*b4.x; acc[2].y += x2*b4.y; acc[2].z += x2*b4.z; acc[2].w += x2*b4.w;
        acc[3].x += x3*b4.x; acc[3].y += x3*b4.y; acc[3].z += x3*b4.z; acc[3].w += x3*b4.w;
      }
    }
    #pragma unroll
    for (int r = 0; r < 4; ++r)
      *(float4*)&Gp[(size_t)(kc*64 + br + r)*NC + c0 + cc] = acc[r];
  } else {
    // ---- fused fc(sfc) path ----
    if (sfc < 0) return;
    __shared__ float oc_l[1024];
    __shared__ float lp[2][128];
    __shared__ float l_l[128];
    int b = blockIdx.x - gemm_nb;
    oc_l[tid]       = h[b*512 + tid];
    oc_l[tid + 256] = h[b*512 + tid + 256];
    int d0 = tid*2;
    float a0 = 0.f, a1 = 0.f;
    #pragma unroll
    for (int cc2 = 0; cc2 < 4; ++cc2){
      float2 p2 = *(const float2*)&ctxp[(size_t)(cc2*64 + b)*512 + d0];
      a0 += p2.x; a1 += p2.y;
    }
    oc_l[512 + d0]     = a0;
    oc_l[512 + d0 + 1] = a1;
    size_t oco = OC_OFF + (size_t)(b*SS + sfc)*1024 + 512 + d0;
    out[oco]     = a0;
    out[oco + 1] = a1;
    __syncthreads();
    int v = tid & 127, half = tid >> 7;
    float acc = 0.f;
    #pragma unroll 8
    for (int k = 0; k < 512; ++k)
      acc += oc_l[half*512 + k] * fcT[(size_t)(half*512 + k)*128 + v];
    lp[half][v] = acc;
    __syncthreads();
    if (tid < 128) l_l[tid] = lp[0][tid] + lp[1][tid] + fc_b[tid];
    __syncthreads();
    if (tid < 128){
      float m = -1e30f;
      for (int i = 0; i < 128; ++i) m = fmaxf(m, l_l[i]);
      float sm = 0.f;
      for (int i = 0; i < 128; ++i) sm += __expf(l_l[i] - m);
      out[(size_t)(b*SS + sfc)*VV + tid] = l_l[tid] - m - __logf(sm);
    }
  }
}

// ---------------- K2: gates -> h_new ; q partials -------------------------
__global__ __launch_bounds__(256) void k_gate_q(const float* __restrict__ Gp,
                                                const float* __restrict__ bias_big,
                                                float* __restrict__ h,
                                                const float* __restrict__ wqT,
                                                float* __restrict__ qp,
                                                float* __restrict__ out, int s){
  __shared__ float h_l[512];
  int tid = threadIdx.x;
  int jt = blockIdx.x, bt = blockIdx.y;
  bool t0 = (s == 0);
  #pragma unroll
  for (int it = 0; it < 2; ++it){
    int item = tid + it*256;
    int bi = item >> 6, jl = item & 63;
    int b = bt*8 + bi, j = jt*64 + jl;
    float s0=0.f, s1=0.f, s2=0.f, s3=0.f;
    #pragma unroll
    for (int kc = 0; kc < 8; ++kc){
      const float* g = Gp + (size_t)(kc*64 + b)*NC;
      s0 += g[j]; s1 += g[512+j]; s2 += g[1024+j]; s3 += g[1536+j];
    }
    float r = sigmoid_f(s0 + bias_big[j]);
    float z = sigmoid_f(s1 + bias_big[512+j]);
    float n = tanh_f(s2 + bias_big[1024+j] + r*(s3 + bias_big[1536+j]));
    float hold = t0 ? 0.f : h[b*512 + j];
    float hn = (1.f - z)*n + z*hold;
    h_l[item] = hn;
    h[b*512 + j] = hn;
    out[OC_OFF + (size_t)(b*SS + s)*1024 + j] = hn;
  }
  __syncthreads();
  int a0 = tid*2;
  float2 acc8[8];
  #pragma unroll
  for (int bi = 0; bi < 8; ++bi) acc8[bi] = make_float2(0.f, 0.f);
  for (int j = 0; j < 64; ++j){
    float2 w = *(const float2*)&wqT[(size_t)(jt*64 + j)*512 + a0];
    #pragma unroll
    for (int bi = 0; bi < 8; ++bi){
      float hv = h_l[bi*64 + j];
      acc8[bi].x += hv*w.x; acc8[bi].y += hv*w.y;
    }
  }
  #pragma unroll
  for (int bi = 0; bi < 8; ++bi)
    *(float2*)&qp[(size_t)(jt*64 + bt*8 + bi)*512 + a0] = acc8[bi];
}

// ---------------- K3: scores --------------------------------------------
__global__ __launch_bounds__(1024) void k_score(const float* __restrict__ qp,
                                                const float* __restrict__ attn_v,
                                                const float* __restrict__ conv_w,
                                                const u16* __restrict__ encp,
                                                const float* __restrict__ out_aw,
                                                float* __restrict__ score, int s){
  __shared__ float q_l[512], v_l[512], c0_l[512], c1_l[512], c2_l[512];
  int tid = threadIdx.x;
  int b = blockIdx.y, et = blockIdx.x;
  if (tid < 512){
    float qq = 0.f;
    #pragma unroll
    for (int jt = 0; jt < 8; ++jt) qq += qp[(size_t)(jt*64 + b)*512 + tid];
    q_l[tid]  = qq;
    v_l[tid]  = attn_v[tid];
    c0_l[tid] = conv_w[tid*3 + 0];
    c1_l[tid] = conv_w[tid*3 + 1];
    c2_l[tid] = conv_w[tid*3 + 2];
  }
  __syncthreads();
  int wave = tid >> 6, lane = tid & 63;
  float q8[8], v8[8], c08[8], c18[8], c28[8];
  #pragma unroll
  for (int i = 0; i < 8; ++i){
    int a = lane*8 + i;
    q8[i] = q_l[a]; v8[i] = v_l[a]; c08[i] = c0_l[a]; c18[i] = c1_l[a]; c28[i] = c2_l[a];
  }
  const float* awrow = out_aw + AW_OFF + (size_t)(b*SS + (s-1))*EE;
  #pragma unroll
  for (int eu = 0; eu < 8; ++eu){
    int e = et*128 + wave*8 + eu;
    float wl = 0.f, wc = 0.f, wr = 0.f;
    if (s > 0){
      wc = awrow[e];
      wl = (e > 0)    ? awrow[e-1] : 0.f;
      wr = (e < EE-1) ? awrow[e+1] : 0.f;
    }
    uint4 pk = *(const uint4*)(encp + ((size_t)(b*EE + e)*512 + lane*8));
    uint32_t ua[4] = {pk.x, pk.y, pk.z, pk.w};
    float acc = 0.f;
    #pragma unroll
    for (int p = 0; p < 4; ++p){
      float plo = __uint_as_float(ua[p] << 16);
      float phi = __uint_as_float(ua[p] & 0xffff0000u);
      int i = p*2;
      float v0 = q8[i]   + plo + c08[i]*wl   + c18[i]*wc   + c28[i]*wr;
      acc += tanh_f(v0) * v8[i];
      float v1 = q8[i+1] + phi + c08[i+1]*wl + c18[i+1]*wc + c28[i+1]*wr;
      acc += tanh_f(v1) * v8[i+1];
    }
    #pragma unroll
    for (int off = 32; off; off >>= 1) acc += __shfl_xor(acc, off, 64);
    if (lane == 0) score[b*EE + e] = acc;
  }
}

// ---------------- K4: softmax + aw out + ctx partials (bf16 enc) ----------
__global__ __launch_bounds__(512) void k_soft_ctx(const float* __restrict__ score,
                                                  const u16* __restrict__ enc_bf,
                                                  float* __restrict__ ctxp,
                                                  float* __restrict__ out, int s){
  __shared__ float s_l[1024];
  __shared__ float red[512];
  __shared__ float w_l[256];
  __shared__ float redc[8][512];
  int tid = threadIdx.x;
  int c = blockIdx.x, b = blockIdx.y;
  float lv0 = score[b*EE + tid];
  float lv1 = score[b*EE + 512 + tid];
  s_l[tid] = lv0; s_l[512 + tid] = lv1;
  float m = fmaxf(lv0, lv1);
  red[tid] = m; __syncthreads();
  for (int st = 256; st > 0; st >>= 1){
    if (tid < st) red[tid] = fmaxf(red[tid], red[tid+st]);
    __syncthreads();
  }
  m = red[0]; __syncthreads();
  float sm = __expf(lv0 - m) + __expf(lv1 - m);
  red[tid] = sm; __syncthreads();
  for (int st = 256; st > 0; st >>= 1){
    if (tid < st) red[tid] += red[tid+st];
    __syncthreads();
  }
  float rS = __builtin_amdgcn_rcpf(red[0]);
  if (tid < 256){
    int e = c*256 + tid;
    float w = __expf(s_l[e] - m) * rS;
    w_l[tid] = w;
    out[AW_OFF + (size_t)(b*SS + s)*EE + e] = w;
  }
  __syncthreads();
  int es = tid >> 6, lane = tid & 63;
  int d0 = lane * 8;
  float acc8[8];
  #pragma unroll
  for (int i = 0; i < 8; ++i) acc8[i] = 0.f;
  #pragma unroll 4
  for (int i = 0; i < 32; ++i){
    int e_loc = es*32 + i;
    int e = c*256 + e_loc;
    uint4 pk = *(const uint4*)(enc_bf + ((size_t)b*EE + e)*512 + d0);
    float w = w_l[e_loc];
    uint32_t ua[4] = {pk.x, pk.y, pk.z, pk.w};
    #pragma unroll
    for (int p = 0; p < 4; ++p){
      acc8[p*2]   += w * __uint_as_float(ua[p] << 16);
      acc8[p*2+1] += w * __uint_as_float(ua[p] & 0xffff0000u);
    }
  }
  #pragma unroll
  for (int i = 0; i < 8; ++i) redc[es][d0 + i] = acc8[i];
  __syncthreads();
  if (tid < 128){
    int d = tid * 4;
    float4 t = make_float4(0.f,0.f,0.f,0.f);
    #pragma unroll
    for (int e2 = 0; e2 < 8; ++e2){
      float4 r4 = *(const float4*)&redc[e2][d];
      t.x += r4.x; t.y += r4.y; t.z += r4.z; t.w += r4.w;
    }
    *(float4*)&ctxp[(size_t)(c*64 + b)*512 + d] = t;
  }
}

extern "C" void kernel_launch(void* const* d_in, const int* in_sizes, int n_in,
                              void* d_out, int out_size, void* d_ws, size_t ws_size,
                              hipStream_t stream){
  (void)in_sizes; (void)n_in; (void)out_size; (void)ws_size;
  const int*   inputs = (const int*)d_in[0];
  const float* enc    = (const float*)d_in[1];
  const float* emb    = (const float*)d_in[2];
  const float* w_ih   = (const float*)d_in[3];
  const float* w_hh   = (const float*)d_in[4];
  const float* b_ih   = (const float*)d_in[5];
  const float* b_hh   = (const float*)d_in[6];
  const float* wq     = (const float*)d_in[7];
  const float* wv     = (const float*)d_in[8];
  const float* convw  = (const float*)d_in[9];
  const float* convb  = (const float*)d_in[10];
  const float* abias  = (const float*)d_in[11];
  const float* av     = (const float*)d_in[12];
  const float* fcw    = (const float*)d_in[13];
  const float* fcb    = (const float*)d_in[14];
  float* out = (float*)d_out;

  char* p = (char*)d_ws;
  auto alloc = [&](size_t bytes)->char*{
    char* r = p; p += (bytes + 255) & ~(size_t)255; return r;
  };
  u16*   encp   = (u16*)  alloc((size_t)BB*EE*AA*2);   // 67 MB
  u16*   enc_bf = (u16*)  alloc((size_t)BB*EE*DD*2);   // 67 MB
  float* Wbig   = (float*)alloc((size_t)KX*NC*4);      // 12.6 MB
  float* wqT    = (float*)alloc((size_t)512*512*4);
  float* wvT    = (float*)alloc((size_t)512*512*4);
  float* fcT    = (float*)alloc((size_t)1024*128*4);
  float* biasb  = (float*)alloc((size_t)NC*4);
  float* hbuf   = (float*)alloc((size_t)BB*HH*4);
  float* Gp     = (float*)alloc((size_t)8*BB*NC*4);    // 4 MB
  float* qp     = (float*)alloc((size_t)8*BB*AA*4);    // 1 MB
  float* score  = (float*)alloc((size_t)BB*EE*4);
  float* ctxp   = (float*)alloc((size_t)4*BB*DD*4);    // 512 KB

  int total0 = KX*NC + 512*512 + 512*512 + 1024*128 + NC;
  k_build<<<(total0 + 255)/256, 256, 0, stream>>>(w_ih, w_hh, b_ih, b_hh, wq, wv, fcw,
                                                  Wbig, wqT, wvT, fcT, biasb);
  k_encp<<<dim3(1024, 8), 256, 0, stream>>>(enc, wvT, abias, convb, encp);
  k_encbf<<<(BB*EE*DD/4 + 255)/256, 256, 0, stream>>>(enc, enc_bf);

  for (int s = 0; s < SS; ++s){
    int sfc = s - 1;
    int grid = (sfc >= 0) ? 320 : 256;
    k_ggemm_fc<<<grid, 256, 0, stream>>>(inputs, emb, ctxp, hbuf, Wbig, Gp,
                                         fcT, fcb, out, s, 256, sfc);
    k_gate_q<<<dim3(8, 8), 256, 0, stream>>>(Gp, biasb, hbuf, wqT, qp, out, s);
    k_score<<<dim3(8, 64), 1024, 0, stream>>>(qp, av, convw, encp, out, score, s);
    k_soft_ctx<<<dim3(4, 64), 512, 0, stream>>>(score, enc_bf, ctxp, out, s);
  }
  // trailing fc for s=127
  k_ggemm_fc<<<64, 256, 0, stream>>>(inputs, emb, ctxp, hbuf, Wbig, Gp,
                                     fcT, fcb, out, 0, 0, SS-1);
}